// Round 12
// baseline (146.029 us; speedup 1.0000x reference)
//
#include <hip/hip_runtime.h>

#define DD 160
#define HH 192
#define WW 160
#define HWs (HH * WW)          // 30720
#define NTOT 9830400.0f        // 2*160*192*160
#define DOUT 20                // output slices per block
#define NIT  28                // DOUT + 8 halo
#define NBLK 960               // 60 * 8 * 2

// ---- SD layout (f16): [parity][row 0..23][g 0..9][ch-slot 0..5], h4 units.
#define SDRS 62
#define SDP  1492
// ---- HS layout (f16): [parity][ch 0..4][row 0..15][g 0..9], h4 units.
#define HSRS 10
#define HSC  162
#define HSP  810

typedef float    v4 __attribute__((ext_vector_type(4)));
typedef _Float16 h4 __attribute__((ext_vector_type(4)));
typedef _Float16 h2 __attribute__((ext_vector_type(2)));
typedef _Float16 h8 __attribute__((ext_vector_type(8)));

// LDS-only barrier: leaves global prefetch loads in flight.
__device__ __forceinline__ void block_sync_lds() {
    __builtin_amdgcn_s_waitcnt(0xc07f);   // vmcnt=63, expcnt=7, lgkmcnt=0
    __builtin_amdgcn_s_barrier();
}
__device__ __forceinline__ v4 up(h4 x) { return __builtin_convertvector(x, v4); }
__device__ __forceinline__ h4 dnp(v4 x) {
    h2 a = __builtin_bit_cast(h2, __builtin_amdgcn_cvt_pkrtz(x[0], x[1]));
    h2 b = __builtin_bit_cast(h2, __builtin_amdgcn_cvt_pkrtz(x[2], x[3]));
    return __builtin_shufflevector(a, b, 0, 1, 2, 3);
}

// Fully-fused NCC, D-first, ONE barrier per iteration -- r6 structure (the
// measured best: stacked dual wave roles, 2-deep parity buffers, 960 blocks,
// 4 blocks/CU, two-kernel reduction) + DEPTH-2 PREFETCH only (r11's merged
// single-kernel reduction FAILED correctness: cross-XCD visibility of the
// partial[] stores was not guaranteed by the release/acquire-counter chain --
// Guideline 16 vindicated; reverted to k3_final).
//   ph1(t)   rt<240 : rolling 9-window D-sums {I,J,II,JJ,IJ} in pure f32;
//            retiring slice re-read from global (L2/L3-resident,
//            bit-identical => exact cancellation); lead+retire loads issued
//            TWO iterations ahead (parity slots, ~2 barrier intervals in
//            flight); writes f16 SD[t&1] as 2xb128+1xb64.
//   ph2(t-1) rt<100 : 9-tap + 8-row slide H-sum over SD[(t-1)&1], packed
//            f16, initial rows reg-kept -> HS[(t-1)&1]
//   ph3(t-2) rt>=128: sliding W-sum over HS[t&1] + cc, 4 outputs/thread
// LDS 37.9 KB -> 4 blocks/CU. XCD-bijective swizzle: 120 tiles per XCD.
__global__ __launch_bounds__(256, 4) void kf(const float* __restrict__ I,
                                             const float* __restrict__ J,
                                             float* __restrict__ partial) {
    __shared__ __align__(16) h4 SDL[2 * SDP];   // 23872 B
    __shared__ __align__(16) h4 HSL[2 * HSP];   // 12960 B
    __shared__ float red[256];                  //  1024 B

    const int tid = threadIdx.x;
    // XCD swizzle: 8 chunks of 120 consecutive linear tile ids.
    const int wgid = blockIdx.x;
    const int tl = (wgid & 7) * 120 + (wgid >> 3);
    const int bx = tl % 60, by = (tl / 60) % 8, b = tl / 480;
    const int w0 = (bx % 5) * 32, h0 = (bx / 5) * 16;
    const int d0 = by * DOUT;
    const int bid = tl;

    const int rt = tid ^ ((bx & 1) << 7);   // role swap waves 0,1 <-> 2,3

    // ---- ph1 decode: 240 columns = 24 rows x 10 f4-cols
    const bool p1 = rt < 240;
    const int r = rt / 10, g = rt % 10;
    const int gh = h0 - 4 + r, gw = w0 - 4 + g * 4;   // gw 16B-aligned
    const bool colOK = p1 && gh >= 0 && gh < HH && gw >= 0 && gw < WW;
    const size_t colOff = (size_t)gh * WW + gw;
    const float* Ib = I + (size_t)b * DD * HWs + colOff;
    const float* Jb = J + (size_t)b * DD * HWs + colOff;
    const int sdwOff = r * SDRS + (r >> 3) * 2 + 6 * g;

    // ---- ph2 decode: 100 tasks = 10 f4cols x 5 ch x 2 h-halves
    const bool p2 = rt < 100;
    const int g2 = rt % 10, ch2 = (rt / 10) % 5, hh0 = (rt / 50) * 8;
    const int sdrOff = hh0 * SDRS + (hh0 >> 3) * 2 + 6 * g2 +
                       (ch2 == 4 ? 4 + (g2 & 1) : ch2);
    const int hswOff = ch2 * HSC + hh0 * HSRS + g2;

    // ---- ph3 decode: 128 tasks = 16 h-rows x 8 w-segments of 4 outputs
    const bool p3 = rt >= 128;
    const int q3 = rt & 127;
    const int hh = q3 >> 3, sg = q3 & 7;
    const int hsrOff = hh * HSRS + sg;

    v4 sd0 = 0.f, sd1 = 0.f, sd2 = 0.f, sd3 = 0.f, sd4 = 0.f;
    // depth-2 prefetch slots by slice parity (static in unrolled loop)
    v4 pLI0 = 0.f, pLJ0 = 0.f, pLI1 = 0.f, pLJ1 = 0.f;
    v4 pOI0 = 0.f, pOJ0 = 0.f, pOI1 = 0.f, pOJ1 = 0.f;
    float acc = 0.f;
    const float inv = 1.0f / 729.0f;

    {   // preload lead slices for t=0 (slot0) and t=1 (slot1)
        const int s0 = d0 - 4;
        if (colOK && s0 >= 0) {
            pLI0 = *(const v4*)(Ib + (size_t)s0 * HWs);
            pLJ0 = *(const v4*)(Jb + (size_t)s0 * HWs);
        }
        const int s1 = d0 - 3;
        if (colOK && s1 >= 0) {
            pLI1 = *(const v4*)(Ib + (size_t)s1 * HWs);
            pLJ1 = *(const v4*)(Jb + (size_t)s1 * HWs);
        }
    }

    // ph1 body for slice t; prefetches lead+retire for slice t+2 into the
    // same parity slots (t and t+2 share parity).
    auto PH1 = [&](int t, v4& pLIs, v4& pLJs, v4& pOIs, v4& pOJs) {
        const v4 cI = pLIs, cJ = pLJs;
        v4 dI = cI, dJv = cJ;
        v4 dII = cI * cI, dJJ = cJ * cJ, dIJ = cI * cJ;
        if (t >= 9) {       // retire slice t-9 via bit-identical re-read
            dI  -= pOIs;        dJv -= pOJs;
            dII -= pOIs * pOIs; dJJ -= pOJs * pOJs; dIJ -= pOIs * pOJs;
        }
        sd0 += dI; sd1 += dJv; sd2 += dII; sd3 += dJJ; sd4 += dIJ;
        h4* const qb = &SDL[(t & 1) * SDP + sdwOff];
        h4 c0 = dnp(sd0), c1 = dnp(sd1), c2 = dnp(sd2), c3 = dnp(sd3);
        *(h8*)qb       = __builtin_shufflevector(c0, c1, 0,1,2,3,4,5,6,7);
        *(h8*)(qb + 2) = __builtin_shufflevector(c2, c3, 0,1,2,3,4,5,6,7);
        qb[4 + (g & 1)] = dnp(sd4);
        // prefetch lead slice for t+2 (global slice d0-4+(t+2))
        pLIs = 0.f; pLJs = 0.f;
        const int sn = d0 - 2 + t;
        if (t + 2 < NIT && colOK && sn >= 0 && sn < DD) {
            pLIs = *(const v4*)(Ib + (size_t)sn * HWs);
            pLJs = *(const v4*)(Jb + (size_t)sn * HWs);
        }
        // prefetch retiring slice for t+2 (global slice d0-13+(t+2))
        pOIs = 0.f; pOJs = 0.f;
        const int so = d0 - 11 + t;
        if (t + 2 >= 9 && t + 2 < NIT && colOK && so >= 0) {
            pOIs = *(const v4*)(Ib + (size_t)so * HWs);
            pOJs = *(const v4*)(Jb + (size_t)so * HWs);
        }
    };

#pragma unroll
    for (int t = 0; t < NIT + 2; ++t) {
        // ---------- ph1(t): f32 D-rolling, write SD[t&1]
        if (t < NIT && p1) {
            if ((t & 1) == 0) PH1(t, pLI0, pLJ0, pOI0, pOJ0);
            else              PH1(t, pLI1, pLJ1, pOI1, pOJ1);
        }

        // ---------- ph2(t-1): packed-f16 H-sums over SD, reg-keep, write HS
        if (t >= 1 && t <= NIT && p2) {
            const int par = (t - 1) & 1;
            const h4* const sdr = &SDL[par * SDP + sdrOff];
            h4* const hsw = &HSL[par * HSP + hswOff];
            h4 keep[7];                 // rows 0..6 of the initial window
            h4 s = sdr[0];
            keep[0] = s;
#pragma unroll
            for (int k = 1; k < 9; ++k) {
                h4 v = sdr[k * SDRS + (k >= 8 ? 2 : 0)];
                if (k < 7) keep[k] = v;
                s += v;
            }
            hsw[0] = s;
#pragma unroll
            for (int j = 1; j < 8; ++j) {
                s += sdr[(j + 8) * SDRS + 2] - keep[j - 1];
                hsw[j * HSRS] = s;
            }
        }

        // ---------- ph3(t-2): f16 W-slide + cc (output depth d0+t-10)
        if (t >= 10 && p3) {
            const h4* const hsr = &HSL[(t & 1) * HSP + hsrOff];
            float w[5][4];
#pragma unroll
            for (int c = 0; c < 5; ++c) {
                v4 fa = up(hsr[c * HSC]);
                v4 fb = up(hsr[c * HSC + 1]);
                v4 fc = up(hsr[c * HSC + 2]);
                float s = fa[0] + fa[1] + fa[2] + fa[3] +
                          fb[0] + fb[1] + fb[2] + fb[3] + fc[0];
                w[c][0] = s;
                s += fc[1] - fa[0]; w[c][1] = s;
                s += fc[2] - fa[1]; w[c][2] = s;
                s += fc[3] - fa[2]; w[c][3] = s;
            }
#pragma unroll
            for (int e = 0; e < 4; ++e) {
                float mu1 = w[0][e] * inv, mu2 = w[1][e] * inv;
                float g1  = fmaf(-mu1, mu1, w[2][e] * inv);
                float g2v = fmaf(-mu2, mu2, w[3][e] * inv);
                float g12 = fmaf(-mu1, mu2, w[4][e] * inv);
                acc += __fdividef(g12 * g12, fmaf(g1, g2v, 1e-5f));
            }
        }

        block_sync_lds();
    }

    red[tid] = acc;     // only p3 threads have nonzero acc
    __syncthreads();
    if (tid < 128) red[tid] += red[tid + 128];
    __syncthreads();
    if (tid < 64) {
        float a = red[tid] + red[tid + 64];
#pragma unroll
        for (int off = 32; off > 0; off >>= 1) a += __shfl_down(a, off);
        if (tid == 0) partial[bid] = a;
    }
}

__global__ void k3_final(const float* __restrict__ partial,
                         float* __restrict__ out) {
    __shared__ float r[1024];
    const int i = threadIdx.x;
    r[i] = (i < NBLK) ? partial[i] : 0.f;
    __syncthreads();
    for (int off = 512; off > 0; off >>= 1) {
        if (i < off) r[i] += r[i + off];
        __syncthreads();
    }
    if (i == 0) out[0] = -r[0] * (1.0f / NTOT);
}

extern "C" void kernel_launch(void* const* d_in, const int* in_sizes, int n_in,
                              void* d_out, int out_size, void* d_ws, size_t ws_size,
                              hipStream_t stream) {
    (void)in_sizes; (void)n_in; (void)out_size; (void)ws_size;
    const float* I = (const float*)d_in[0];   // y_true
    const float* J = (const float*)d_in[1];   // y_pred
    float* out     = (float*)d_out;
    float* partial = (float*)d_ws;            // NBLK floats, all written

    kf<<<dim3(NBLK), 256, 0, stream>>>(I, J, partial);
    k3_final<<<1, 1024, 0, stream>>>(partial, out);
}

// Round 13
// 145.557 us; speedup vs baseline: 1.0032x; 1.0032x over previous
//
#include <hip/hip_runtime.h>

#define DD 160
#define HH 192
#define WW 160
#define HWs (HH * WW)          // 30720
#define NTOT 9830400.0f        // 2*160*192*160
#define DOUT 20                // output slices per block
#define NIT  28                // DOUT + 8 halo
#define NBLK 960               // 60 * 8 * 2

// ---- SD layout (f16): [parity][row 0..23][g 0..9][ch 0..4], h4 units.
// Inner = 5g+ch (stride-5, NO slack slot, NO displaced ch4). Row stride 50
// + 2 pad per 8-row group ((r>>3)*2). ph1 writes 5xb64; ph2 lanes remapped
// (g2=l/5, ch2=l%5) so each tap read is addr = base_k + l: STRIDE-1 across
// 50 lanes -- conflict-free by construction, not by stride-tuning.
#define SDRS 50
#define SDP  1204
// ---- HS layout (f16): [parity][ch 0..4][row 0..15][g 0..9], h4 units.
#define HSRS 10
#define HSC  162
#define HSP  810

typedef float    v4 __attribute__((ext_vector_type(4)));
typedef _Float16 h4 __attribute__((ext_vector_type(4)));
typedef _Float16 h2 __attribute__((ext_vector_type(2)));

// LDS-only barrier: leaves global prefetch loads in flight.
__device__ __forceinline__ void block_sync_lds() {
    __builtin_amdgcn_s_waitcnt(0xc07f);   // vmcnt=63, expcnt=7, lgkmcnt=0
    __builtin_amdgcn_s_barrier();
}
__device__ __forceinline__ v4 up(h4 x) { return __builtin_convertvector(x, v4); }
__device__ __forceinline__ h4 dnp(v4 x) {
    h2 a = __builtin_bit_cast(h2, __builtin_amdgcn_cvt_pkrtz(x[0], x[1]));
    h2 b = __builtin_bit_cast(h2, __builtin_amdgcn_cvt_pkrtz(x[2], x[3]));
    return __builtin_shufflevector(a, b, 0, 1, 2, 3);
}

// Fully-fused NCC, D-first, ONE barrier per iteration -- r6 structure (the
// measured best: stacked dual wave roles, 2-deep parity buffers, 960 blocks,
// 4 blocks/CU, depth-1 prefetch, two-kernel reduction) with the SD tile
// RELAID OUT for provably-clean LDS patterns. Accounting (r12): LDS pipe is
// ~96% busy and conflict-replay cycles (271/block-iter) exceed clean data
// cycles (~180) -- the binding resource. ph2's read clusters (old inner
// 6g+ch with lane map g2=l%10 put 2 lanes on the same bank-pair per decade)
// and ph1's b128 writes (12g%32 collides g0/g8,g1/g9) were the clumps.
//   ph1(t)   rt<240 : rolling 9-window D-sums {I,J,II,JJ,IJ} in pure f32;
//            retiring slice re-read from global (L2/L3-resident,
//            bit-identical => exact cancellation); writes f16 SD[t&1] as
//            5xb64 at banks (2r+5g+c)%16 -- both strides distinct mod 16.
//   ph2(t-1) rt<100 : 9-tap + 8-row slide H-sum over SD[(t-1)&1], packed
//            f16, initial rows reg-kept; reads stride-1 -> HS[(t-1)&1]
//   ph3(t-2) rt>=128: sliding W-sum over HS[t&1] + cc, 4 outputs/thread
// LDS 33.2 KB -> 4 blocks/CU. XCD-bijective swizzle: 120 tiles per XCD.
__global__ __launch_bounds__(256, 4) void kf(const float* __restrict__ I,
                                             const float* __restrict__ J,
                                             float* __restrict__ partial) {
    __shared__ __align__(16) h4 SDL[2 * SDP];   // 19264 B
    __shared__ __align__(16) h4 HSL[2 * HSP];   // 12960 B
    __shared__ float red[256];                  //  1024 B

    const int tid = threadIdx.x;
    // XCD swizzle: 8 chunks of 120 consecutive linear tile ids.
    const int wgid = blockIdx.x;
    const int tl = (wgid & 7) * 120 + (wgid >> 3);
    const int bx = tl % 60, by = (tl / 60) % 8, b = tl / 480;
    const int w0 = (bx % 5) * 32, h0 = (bx / 5) * 16;
    const int d0 = by * DOUT;
    const int bid = tl;

    const int rt = tid ^ ((bx & 1) << 7);   // role swap waves 0,1 <-> 2,3

    // ---- ph1 decode: 240 columns = 24 rows x 10 f4-cols
    const bool p1 = rt < 240;
    const int r = rt / 10, g = rt % 10;
    const int gh = h0 - 4 + r, gw = w0 - 4 + g * 4;   // gw 16B-aligned
    const bool colOK = p1 && gh >= 0 && gh < HH && gw >= 0 && gw < WW;
    const size_t colOff = (size_t)gh * WW + gw;
    const float* Ib = I + (size_t)b * DD * HWs + colOff;
    const float* Jb = J + (size_t)b * DD * HWs + colOff;
    const int sdwOff = r * SDRS + (r >> 3) * 2 + 5 * g;

    // ---- ph2 decode: 100 tasks = 2 h-halves x 50 inner (g2=inner/5, ch2=inner%5)
    const bool p2 = rt < 100;
    const int inn2 = rt % 50, hh0 = (rt / 50) * 8;
    const int g2 = inn2 / 5, ch2 = inn2 % 5;
    const int sdrOff = hh0 * SDRS + (hh0 >> 3) * 2 + inn2;   // stride-1 lanes
    const int hswOff = ch2 * HSC + hh0 * HSRS + g2;

    // ---- ph3 decode: 128 tasks = 16 h-rows x 8 w-segments of 4 outputs
    const bool p3 = rt >= 128;
    const int q3 = rt & 127;
    const int hh = q3 >> 3, sg = q3 & 7;
    const int hsrOff = hh * HSRS + sg;

    v4 sd0 = 0.f, sd1 = 0.f, sd2 = 0.f, sd3 = 0.f, sd4 = 0.f;
    v4 pLI = 0.f, pLJ = 0.f;   // lead-slice prefetch (slice d0-4+t)
    v4 pOI = 0.f, pOJ = 0.f;   // retiring-slice re-read prefetch
    float acc = 0.f;
    const float inv = 1.0f / 729.0f;

    {   // preload lead slice for t=0
        const int si = d0 - 4;
        if (colOK && si >= 0) {
            pLI = *(const v4*)(Ib + (size_t)si * HWs);
            pLJ = *(const v4*)(Jb + (size_t)si * HWs);
        }
    }

#pragma unroll
    for (int t = 0; t < NIT + 2; ++t) {
        // ---------- ph1(t): f32 D-rolling, write SD[t&1]
        if (t < NIT && p1) {
            const v4 cI = pLI, cJ = pLJ;
            v4 dI = cI, dJv = cJ;
            v4 dII = cI * cI, dJJ = cJ * cJ, dIJ = cI * cJ;
            if (t >= 9) {       // retire slice t-9 via bit-identical re-read
                dI  -= pOI;        dJv -= pOJ;
                dII -= pOI * pOI;  dJJ -= pOJ * pOJ;  dIJ -= pOI * pOJ;
            }
            sd0 += dI; sd1 += dJv; sd2 += dII; sd3 += dJJ; sd4 += dIJ;
            h4* const qb = &SDL[(t & 1) * SDP + sdwOff];
            qb[0] = dnp(sd0);
            qb[1] = dnp(sd1);
            qb[2] = dnp(sd2);
            qb[3] = dnp(sd3);
            qb[4] = dnp(sd4);
            // prefetch lead slice for t+1 (in flight across barrier)
            pLI = 0.f; pLJ = 0.f;
            const int sn = d0 - 3 + t;
            if (t + 1 < NIT && colOK && sn >= 0 && sn < DD) {
                pLI = *(const v4*)(Ib + (size_t)sn * HWs);
                pLJ = *(const v4*)(Jb + (size_t)sn * HWs);
            }
            // prefetch retiring slice for t+1 (L2/L3 hit)
            pOI = 0.f; pOJ = 0.f;
            const int so = d0 - 12 + t;
            if (t >= 8 && t + 1 < NIT && colOK && so >= 0) {
                pOI = *(const v4*)(Ib + (size_t)so * HWs);
                pOJ = *(const v4*)(Jb + (size_t)so * HWs);
            }
        }

        // ---------- ph2(t-1): packed-f16 H-sums over SD (stride-1 reads),
        //            reg-keep, write HS
        if (t >= 1 && t <= NIT && p2) {
            const int par = (t - 1) & 1;
            const h4* const sdr = &SDL[par * SDP + sdrOff];
            h4* const hsw = &HSL[par * HSP + hswOff];
            h4 keep[7];                 // rows 0..6 of the initial window
            h4 s = sdr[0];
            keep[0] = s;
#pragma unroll
            for (int k = 1; k < 9; ++k) {
                h4 v = sdr[k * SDRS + (k >= 8 ? 2 : 0)];
                if (k < 7) keep[k] = v;
                s += v;
            }
            hsw[0] = s;
#pragma unroll
            for (int j = 1; j < 8; ++j) {
                s += sdr[(j + 8) * SDRS + 2] - keep[j - 1];
                hsw[j * HSRS] = s;
            }
        }

        // ---------- ph3(t-2): f16 W-slide + cc (output depth d0+t-10)
        if (t >= 10 && p3) {
            const h4* const hsr = &HSL[(t & 1) * HSP + hsrOff];
            float w[5][4];
#pragma unroll
            for (int c = 0; c < 5; ++c) {
                v4 fa = up(hsr[c * HSC]);
                v4 fb = up(hsr[c * HSC + 1]);
                v4 fc = up(hsr[c * HSC + 2]);
                float s = fa[0] + fa[1] + fa[2] + fa[3] +
                          fb[0] + fb[1] + fb[2] + fb[3] + fc[0];
                w[c][0] = s;
                s += fc[1] - fa[0]; w[c][1] = s;
                s += fc[2] - fa[1]; w[c][2] = s;
                s += fc[3] - fa[2]; w[c][3] = s;
            }
#pragma unroll
            for (int e = 0; e < 4; ++e) {
                float mu1 = w[0][e] * inv, mu2 = w[1][e] * inv;
                float g1  = fmaf(-mu1, mu1, w[2][e] * inv);
                float g2v = fmaf(-mu2, mu2, w[3][e] * inv);
                float g12 = fmaf(-mu1, mu2, w[4][e] * inv);
                acc += __fdividef(g12 * g12, fmaf(g1, g2v, 1e-5f));
            }
        }

        block_sync_lds();
    }

    red[tid] = acc;     // only p3 threads have nonzero acc
    __syncthreads();
    if (tid < 128) red[tid] += red[tid + 128];
    __syncthreads();
    if (tid < 64) {
        float a = red[tid] + red[tid + 64];
#pragma unroll
        for (int off = 32; off > 0; off >>= 1) a += __shfl_down(a, off);
        if (tid == 0) partial[bid] = a;
    }
}

__global__ void k3_final(const float* __restrict__ partial,
                         float* __restrict__ out) {
    __shared__ float r[1024];
    const int i = threadIdx.x;
    r[i] = (i < NBLK) ? partial[i] : 0.f;
    __syncthreads();
    for (int off = 512; off > 0; off >>= 1) {
        if (i < off) r[i] += r[i + off];
        __syncthreads();
    }
    if (i == 0) out[0] = -r[0] * (1.0f / NTOT);
}

extern "C" void kernel_launch(void* const* d_in, const int* in_sizes, int n_in,
                              void* d_out, int out_size, void* d_ws, size_t ws_size,
                              hipStream_t stream) {
    (void)in_sizes; (void)n_in; (void)out_size; (void)ws_size;
    const float* I = (const float*)d_in[0];   // y_true
    const float* J = (const float*)d_in[1];   // y_pred
    float* out     = (float*)d_out;
    float* partial = (float*)d_ws;            // NBLK floats, all written

    kf<<<dim3(NBLK), 256, 0, stream>>>(I, J, partial);
    k3_final<<<1, 1024, 0, stream>>>(partial, out);
}

// Round 14
// 141.853 us; speedup vs baseline: 1.0294x; 1.0261x over previous
//
#include <hip/hip_runtime.h>

#define DD 160
#define HH 192
#define WW 160
#define HWs (HH * WW)          // 30720
#define NTOT 9830400.0f        // 2*160*192*160
#define DOUT 20                // output slices per block
#define NIT  28                // DOUT + 8 halo
#define NBLK 960               // 60 * 8 * 2

// ---- SD layout (f16): [parity][row 0..23][inner=5g+ch 0..49], h4 units.
// Row stride 50 + 2 pad per 8-row group. ph1 writes 5xb64 (flat residues);
// ph2 lanes (g2=l/5, ch2=l%5) read STRIDE-1 across 50 lanes.
#define SDRS 50
#define SDP  1204
// ---- HS layout (f16): [parity][row 0..15][inner=5g+ch 0..49], h4 units.
// Row stride 54 (50 + 4 pad). ph2 writes STRIDE-1 across 50 lanes; ph3
// reads at hh*54 + 5*sg + 5i + c: 54=6 mod 16 -> 6*hh covers all 8 even
// residues, 5*sg distinct mod 16 -> exactly 4 lanes/bank-pair (b64 floor).
#define HSRS 54
#define HSP  864

typedef float    v4 __attribute__((ext_vector_type(4)));
typedef _Float16 h4 __attribute__((ext_vector_type(4)));
typedef _Float16 h2 __attribute__((ext_vector_type(2)));

// LDS-only barrier: leaves global prefetch loads in flight.
__device__ __forceinline__ void block_sync_lds() {
    __builtin_amdgcn_s_waitcnt(0xc07f);   // vmcnt=63, expcnt=7, lgkmcnt=0
    __builtin_amdgcn_s_barrier();
}
__device__ __forceinline__ v4 up(h4 x) { return __builtin_convertvector(x, v4); }
__device__ __forceinline__ h4 dnp(v4 x) {
    h2 a = __builtin_bit_cast(h2, __builtin_amdgcn_cvt_pkrtz(x[0], x[1]));
    h2 b = __builtin_bit_cast(h2, __builtin_amdgcn_cvt_pkrtz(x[2], x[3]));
    return __builtin_shufflevector(a, b, 0, 1, 2, 3);
}

// Fully-fused NCC, D-first, ONE barrier per iteration -- r6 structure (the
// measured best: stacked dual wave roles, 2-deep parity buffers, 960 blocks,
// 4 blocks/CU, depth-1 prefetch, two-kernel reduction) with BOTH staging
// tiles laid out for construction-clean LDS patterns (r13: SD relayout cut
// conflicts 7.8M->3.5M, kf 65.8->63.4; this round removes the identified
// remainder, ph2's HS-write clump (2c+g triangular residues, 5-6 lanes/pair)
// via HS inner=5g+ch with stride-1 writes).
//   ph1(t)   rt<240 : rolling 9-window D-sums {I,J,II,JJ,IJ} in pure f32;
//            retiring slice re-read from global (L2/L3-resident,
//            bit-identical => exact cancellation); writes f16 SD[t&1] 5xb64.
//   ph2(t-1) rt<100 : 9-tap + 8-row slide H-sum over SD[(t-1)&1], packed
//            f16, initial rows reg-kept; stride-1 reads AND writes.
//   ph3(t-2) rt>=128: sliding W-sum over HS[t&1] (flat-4 reads) + cc.
// LDS 33.3 KB -> 4 blocks/CU. XCD-bijective swizzle: 120 tiles per XCD.
__global__ __launch_bounds__(256, 4) void kf(const float* __restrict__ I,
                                             const float* __restrict__ J,
                                             float* __restrict__ partial) {
    __shared__ __align__(16) h4 SDL[2 * SDP];   // 19264 B
    __shared__ __align__(16) h4 HSL[2 * HSP];   // 13824 B
    __shared__ float red[256];                  //  1024 B

    const int tid = threadIdx.x;
    // XCD swizzle: 8 chunks of 120 consecutive linear tile ids.
    const int wgid = blockIdx.x;
    const int tl = (wgid & 7) * 120 + (wgid >> 3);
    const int bx = tl % 60, by = (tl / 60) % 8, b = tl / 480;
    const int w0 = (bx % 5) * 32, h0 = (bx / 5) * 16;
    const int d0 = by * DOUT;
    const int bid = tl;

    const int rt = tid ^ ((bx & 1) << 7);   // role swap waves 0,1 <-> 2,3

    // ---- ph1 decode: 240 columns = 24 rows x 10 f4-cols
    const bool p1 = rt < 240;
    const int r = rt / 10, g = rt % 10;
    const int gh = h0 - 4 + r, gw = w0 - 4 + g * 4;   // gw 16B-aligned
    const bool colOK = p1 && gh >= 0 && gh < HH && gw >= 0 && gw < WW;
    const size_t colOff = (size_t)gh * WW + gw;
    const float* Ib = I + (size_t)b * DD * HWs + colOff;
    const float* Jb = J + (size_t)b * DD * HWs + colOff;
    const int sdwOff = r * SDRS + (r >> 3) * 2 + 5 * g;

    // ---- ph2 decode: 100 tasks = 2 h-halves x 50 inner (g2=in/5, ch2=in%5)
    const bool p2 = rt < 100;
    const int inn2 = rt % 50, hh0 = (rt / 50) * 8;
    const int sdrOff = hh0 * SDRS + (hh0 >> 3) * 2 + inn2;   // stride-1 lanes
    const int hswOff = hh0 * HSRS + inn2;                    // stride-1 lanes

    // ---- ph3 decode: 128 tasks = 16 h-rows x 8 w-segments of 4 outputs
    const bool p3 = rt >= 128;
    const int q3 = rt & 127;
    const int hh = q3 >> 3, sg = q3 & 7;
    const int hsrOff = hh * HSRS + 5 * sg;

    v4 sd0 = 0.f, sd1 = 0.f, sd2 = 0.f, sd3 = 0.f, sd4 = 0.f;
    v4 pLI = 0.f, pLJ = 0.f;   // lead-slice prefetch (slice d0-4+t)
    v4 pOI = 0.f, pOJ = 0.f;   // retiring-slice re-read prefetch
    float acc = 0.f;
    const float inv = 1.0f / 729.0f;

    {   // preload lead slice for t=0
        const int si = d0 - 4;
        if (colOK && si >= 0) {
            pLI = *(const v4*)(Ib + (size_t)si * HWs);
            pLJ = *(const v4*)(Jb + (size_t)si * HWs);
        }
    }

#pragma unroll
    for (int t = 0; t < NIT + 2; ++t) {
        // ---------- ph1(t): f32 D-rolling, write SD[t&1]
        if (t < NIT && p1) {
            const v4 cI = pLI, cJ = pLJ;
            v4 dI = cI, dJv = cJ;
            v4 dII = cI * cI, dJJ = cJ * cJ, dIJ = cI * cJ;
            if (t >= 9) {       // retire slice t-9 via bit-identical re-read
                dI  -= pOI;        dJv -= pOJ;
                dII -= pOI * pOI;  dJJ -= pOJ * pOJ;  dIJ -= pOI * pOJ;
            }
            sd0 += dI; sd1 += dJv; sd2 += dII; sd3 += dJJ; sd4 += dIJ;
            h4* const qb = &SDL[(t & 1) * SDP + sdwOff];
            qb[0] = dnp(sd0);
            qb[1] = dnp(sd1);
            qb[2] = dnp(sd2);
            qb[3] = dnp(sd3);
            qb[4] = dnp(sd4);
            // prefetch lead slice for t+1 (in flight across barrier)
            pLI = 0.f; pLJ = 0.f;
            const int sn = d0 - 3 + t;
            if (t + 1 < NIT && colOK && sn >= 0 && sn < DD) {
                pLI = *(const v4*)(Ib + (size_t)sn * HWs);
                pLJ = *(const v4*)(Jb + (size_t)sn * HWs);
            }
            // prefetch retiring slice for t+1 (L2/L3 hit)
            pOI = 0.f; pOJ = 0.f;
            const int so = d0 - 12 + t;
            if (t >= 8 && t + 1 < NIT && colOK && so >= 0) {
                pOI = *(const v4*)(Ib + (size_t)so * HWs);
                pOJ = *(const v4*)(Jb + (size_t)so * HWs);
            }
        }

        // ---------- ph2(t-1): packed-f16 H-sums over SD (stride-1 reads),
        //            reg-keep, stride-1 writes -> HS
        if (t >= 1 && t <= NIT && p2) {
            const int par = (t - 1) & 1;
            const h4* const sdr = &SDL[par * SDP + sdrOff];
            h4* const hsw = &HSL[par * HSP + hswOff];
            h4 keep[7];                 // rows 0..6 of the initial window
            h4 s = sdr[0];
            keep[0] = s;
#pragma unroll
            for (int k = 1; k < 9; ++k) {
                h4 v = sdr[k * SDRS + (k >= 8 ? 2 : 0)];
                if (k < 7) keep[k] = v;
                s += v;
            }
            hsw[0] = s;
#pragma unroll
            for (int j = 1; j < 8; ++j) {
                s += sdr[(j + 8) * SDRS + 2] - keep[j - 1];
                hsw[j * HSRS] = s;
            }
        }

        // ---------- ph3(t-2): f16 W-slide + cc (output depth d0+t-10)
        if (t >= 10 && p3) {
            const h4* const hsr = &HSL[(t & 1) * HSP + hsrOff];
            float w[5][4];
#pragma unroll
            for (int c = 0; c < 5; ++c) {
                v4 fa = up(hsr[c]);
                v4 fb = up(hsr[c + 5]);
                v4 fc = up(hsr[c + 10]);
                float s = fa[0] + fa[1] + fa[2] + fa[3] +
                          fb[0] + fb[1] + fb[2] + fb[3] + fc[0];
                w[c][0] = s;
                s += fc[1] - fa[0]; w[c][1] = s;
                s += fc[2] - fa[1]; w[c][2] = s;
                s += fc[3] - fa[2]; w[c][3] = s;
            }
#pragma unroll
            for (int e = 0; e < 4; ++e) {
                float mu1 = w[0][e] * inv, mu2 = w[1][e] * inv;
                float g1  = fmaf(-mu1, mu1, w[2][e] * inv);
                float g2v = fmaf(-mu2, mu2, w[3][e] * inv);
                float g12 = fmaf(-mu1, mu2, w[4][e] * inv);
                acc += __fdividef(g12 * g12, fmaf(g1, g2v, 1e-5f));
            }
        }

        block_sync_lds();
    }

    red[tid] = acc;     // only p3 threads have nonzero acc
    __syncthreads();
    if (tid < 128) red[tid] += red[tid + 128];
    __syncthreads();
    if (tid < 64) {
        float a = red[tid] + red[tid + 64];
#pragma unroll
        for (int off = 32; off > 0; off >>= 1) a += __shfl_down(a, off);
        if (tid == 0) partial[bid] = a;
    }
}

__global__ void k3_final(const float* __restrict__ partial,
                         float* __restrict__ out) {
    __shared__ float r[1024];
    const int i = threadIdx.x;
    r[i] = (i < NBLK) ? partial[i] : 0.f;
    __syncthreads();
    for (int off = 512; off > 0; off >>= 1) {
        if (i < off) r[i] += r[i + off];
        __syncthreads();
    }
    if (i == 0) out[0] = -r[0] * (1.0f / NTOT);
}

extern "C" void kernel_launch(void* const* d_in, const int* in_sizes, int n_in,
                              void* d_out, int out_size, void* d_ws, size_t ws_size,
                              hipStream_t stream) {
    (void)in_sizes; (void)n_in; (void)out_size; (void)ws_size;
    const float* I = (const float*)d_in[0];   // y_true
    const float* J = (const float*)d_in[1];   // y_pred
    float* out     = (float*)d_out;
    float* partial = (float*)d_ws;            // NBLK floats, all written

    kf<<<dim3(NBLK), 256, 0, stream>>>(I, J, partial);
    k3_final<<<1, 1024, 0, stream>>>(partial, out);
}